// Round 3
// baseline (84.418 us; speedup 1.0000x reference)
//
#include <hip/hip_runtime.h>
#include <hip/hip_cooperative_groups.h>

namespace cg = cooperative_groups;

#define HW 512

__device__ __forceinline__ float prelu(float x, float a) { return x >= 0.f ? x : a * x; }

// ---------------- Fused cooperative kernel ----------------
// 256 blocks x 1024 threads, 1 block/CU. Block bid: batch = bid/32, stripe = bid%32
// covers output rows r0..r0+15 (16x512 pixels). s kept in LDS; grid.sync();
// gate computed redundantly per block (deterministic); scale + write.
__global__ __launch_bounds__(1024) void fused(
    const float* __restrict__ in1, const float* __restrict__ in2, const float* __restrict__ in3,
    const float* __restrict__ Wd, const float* __restrict__ bd, const float* __restrict__ ad,
    const float* __restrict__ Wu, const float* __restrict__ bu, const float* __restrict__ au,
    const float* __restrict__ Wc, const float* __restrict__ bc, const float* __restrict__ ag,
    float* __restrict__ out, float* __restrict__ ws)
{
    extern __shared__ float smem[];
    float* s_lds = smem;             // 16*512*3 = 24576 floats
    float* d1    = smem + 24576;     // 3 slots * 513*3 = 4617 floats (rolling ring)
    float* red   = d1 + 4617;        // 16*3
    float* ybuf  = red + 48;         // 3

    const int tid    = threadIdx.x;
    const int bid    = blockIdx.x;
    const int batch  = bid >> 5;
    const int stripe = bid & 31;
    const int r0     = stripe * 16;

    float wd[9], wu[9];
    #pragma unroll
    for (int k = 0; k < 9; k++) { wd[k] = Wd[k]; wu[k] = Wu[k]; }
    const float bd0 = bd[0], bd1 = bd[1], bd2 = bd[2];
    const float ad0 = ad[0], ad1 = ad[1], ad2 = ad[2];
    const float bu0 = bu[0], bu1 = bu[1], bu2 = bu[2];
    const float au0 = au[0], au1 = au[1], au2 = au[2];
    const float cu0 = prelu(bu0, au0), cu1 = prelu(bu1, au1), cu2 = prelu(bu2, au2);

    float p0 = 0.f, p1 = 0.f, p2 = 0.f;
    const int lrOff = tid >> 9;     // 0/1
    const int col   = tid & 511;

    for (int i = 0; i < 8; i++) {
        // d1 rows needed this iter: 2i, 2i+1, 2i+2. Rows <=2i already present.
        const int drStart = (i == 0) ? 0 : (2 * i + 1);
        const int n = (2 * i + 2 - drStart + 1) * 513;
        __syncthreads();   // guard: prev iter's reads done before ring overwrite
        for (int e = tid; e < n; e += 1024) {
            const int dr = drStart + e / 513;
            const int c  = e - (e / 513) * 513;
            const int gh = r0 + dr;
            float v0 = -INFINITY, v1 = -INFINITY, v2 = -INFINITY;
            if (gh < HW && c < HW) {
                const float* p = in1 + ((batch * 1024 + 2 * gh) * 1024 + 2 * c) * 3;
                const float x0 = p[0], x1 = p[1], x2 = p[2];
                v0 = prelu(x0 * wd[0] + x1 * wd[3] + x2 * wd[6] + bd0, ad0);
                v1 = prelu(x0 * wd[1] + x1 * wd[4] + x2 * wd[7] + bd1, ad1);
                v2 = prelu(x0 * wd[2] + x1 * wd[5] + x2 * wd[8] + bd2, ad2);
            }
            float* q = d1 + (dr % 3) * 1539 + c * 3;
            q[0] = v0; q[1] = v1; q[2] = v2;
        }
        __syncthreads();

        const int lr  = 2 * i + lrOff;          // local output row 0..15
        const int row = r0 + lr;                // global row
        const float* ra = d1 + (lr % 3) * 1539 + col * 3;
        const float* rb = d1 + ((lr + 1) % 3) * 1539 + col * 3;
        float i1c0 = fmaxf(fmaxf(ra[0], ra[3]), fmaxf(rb[0], rb[3]));
        float i1c1 = fmaxf(fmaxf(ra[1], ra[4]), fmaxf(rb[1], rb[4]));
        float i1c2 = fmaxf(fmaxf(ra[2], ra[5]), fmaxf(rb[2], rb[5]));

        float i3c0 = cu0, i3c1 = cu1, i3c2 = cu2;
        const int he = row + (row & 1), we = col + (col & 1);
        if (he < HW && we < HW) {
            const float* p = in3 + ((batch * 256 + (he >> 1)) * 256 + (we >> 1)) * 3;
            const float x0 = p[0], x1 = p[1], x2 = p[2];
            i3c0 = fmaxf(i3c0, prelu(x0 * wu[0] + x1 * wu[3] + x2 * wu[6] + bu0, au0));
            i3c1 = fmaxf(i3c1, prelu(x0 * wu[1] + x1 * wu[4] + x2 * wu[7] + bu1, au1));
            i3c2 = fmaxf(i3c2, prelu(x0 * wu[2] + x1 * wu[5] + x2 * wu[8] + bu2, au2));
        }

        const float* q2 = in2 + ((batch * HW + row) * HW + col) * 3;
        const float s0 = i1c0 + q2[0] + i3c0;
        const float s1 = i1c1 + q2[1] + i3c1;
        const float s2 = i1c2 + q2[2] + i3c2;
        float* qs = s_lds + (lr * 512 + col) * 3;
        qs[0] = s0; qs[1] = s1; qs[2] = s2;
        p0 += s0; p1 += s1; p2 += s2;
    }

    // deterministic block reduction
    #pragma unroll
    for (int off = 32; off > 0; off >>= 1) {
        p0 += __shfl_down(p0, off);
        p1 += __shfl_down(p1, off);
        p2 += __shfl_down(p2, off);
    }
    const int lane = tid & 63, wv = tid >> 6;
    if (lane == 0) { red[wv * 3 + 0] = p0; red[wv * 3 + 1] = p1; red[wv * 3 + 2] = p2; }
    __syncthreads();
    if (tid == 0) {
        float t0 = 0.f, t1 = 0.f, t2 = 0.f;
        for (int k = 0; k < 16; k++) { t0 += red[k * 3]; t1 += red[k * 3 + 1]; t2 += red[k * 3 + 2]; }
        ws[bid * 3 + 0] = t0; ws[bid * 3 + 1] = t1; ws[bid * 3 + 2] = t2;
        __threadfence();
    }

    cg::this_grid().sync();

    // gate: redundant per block, identical order across the 32 blocks of a batch
    if (tid == 0) {
        float g0 = 0.f, g1 = 0.f, g2 = 0.f;
        const float* pw = ws + batch * 96;
        for (int k = 0; k < 32; k++) { g0 += pw[k * 3]; g1 += pw[k * 3 + 1]; g2 += pw[k * 3 + 2]; }
        const float inv_n = 1.f / (float)(HW * HW);
        g0 *= inv_n; g1 *= inv_n; g2 *= inv_n;
        const float x0 = prelu(g0 * Wc[0] + g1 * Wc[3] + g2 * Wc[6] + bc[0], ag[0]);
        const float x1 = prelu(g0 * Wc[1] + g1 * Wc[4] + g2 * Wc[7] + bc[1], ag[1]);
        const float x2 = prelu(g0 * Wc[2] + g1 * Wc[5] + g2 * Wc[8] + bc[2], ag[2]);
        const float q0 = x0 * Wc[0] + x1 * Wc[3] + x2 * Wc[6] + bc[0];
        const float q1 = x0 * Wc[1] + x1 * Wc[4] + x2 * Wc[7] + bc[1];
        const float q2 = x0 * Wc[2] + x1 * Wc[5] + x2 * Wc[8] + bc[2];
        const float m  = fmaxf(q0, fmaxf(q1, q2));
        const float e0 = expf(q0 - m), e1 = expf(q1 - m), e2 = expf(q2 - m);
        const float inv = 1.f / (e0 + e1 + e2);
        ybuf[0] = e0 * inv; ybuf[1] = e1 * inv; ybuf[2] = e2 * inv;
    }
    __syncthreads();
    const float ym[3] = { ybuf[0], ybuf[1], ybuf[2] };

    // scale + write: block chunk = 24576 floats = 6144 float4
    float4* og = (float4*)(out + (size_t)bid * 24576);
    #pragma unroll
    for (int k = 0; k < 6; k++) {
        const int idx = k * 1024 + tid;
        const int c0  = idx % 3;                 // channel of .x (24576*bid % 3 == 0, 4%3==1)
        float4 v = *((const float4*)s_lds + idx);
        v.x *= ym[c0];
        v.y *= ym[c0 == 2 ? 0 : c0 + 1];
        v.z *= ym[c0 == 0 ? 2 : c0 - 1];
        v.w *= ym[c0];
        og[idx] = v;
    }
}

// ---------------- Fallback: proven 3-kernel path ----------------
__global__ __launch_bounds__(256) void k1_compute_s(
    const float* __restrict__ in1, const float* __restrict__ in2, const float* __restrict__ in3,
    const float* __restrict__ Wd, const float* __restrict__ bd, const float* __restrict__ ad,
    const float* __restrict__ Wu, const float* __restrict__ bu, const float* __restrict__ au,
    float* __restrict__ s_out, float* __restrict__ partials)
{
    const int b  = blockIdx.z;
    const int h0 = blockIdx.y * 16, w0 = blockIdx.x * 16;
    const int tid = threadIdx.x;
    __shared__ float d1[17][17][3];
    for (int idx = tid; idx < 17 * 17; idx += 256) {
        const int ty = idx / 17, tx = idx % 17;
        const int gh = h0 + ty, gw = w0 + tx;
        float v0 = -INFINITY, v1 = -INFINITY, v2 = -INFINITY;
        if (gh < HW && gw < HW) {
            const float* p = in1 + (((b * 1024 + 2 * gh) * 1024 + 2 * gw) * 3);
            const float x0 = p[0], x1 = p[1], x2 = p[2];
            v0 = prelu(x0 * Wd[0] + x1 * Wd[3] + x2 * Wd[6] + bd[0], ad[0]);
            v1 = prelu(x0 * Wd[1] + x1 * Wd[4] + x2 * Wd[7] + bd[1], ad[1]);
            v2 = prelu(x0 * Wd[2] + x1 * Wd[5] + x2 * Wd[8] + bd[2], ad[2]);
        }
        d1[ty][tx][0] = v0; d1[ty][tx][1] = v1; d1[ty][tx][2] = v2;
    }
    __syncthreads();
    const int ty = tid >> 4, tx = tid & 15;
    const int h = h0 + ty, w = w0 + tx;
    float i1c0 = fmaxf(fmaxf(d1[ty][tx][0], d1[ty][tx + 1][0]), fmaxf(d1[ty + 1][tx][0], d1[ty + 1][tx + 1][0]));
    float i1c1 = fmaxf(fmaxf(d1[ty][tx][1], d1[ty][tx + 1][1]), fmaxf(d1[ty + 1][tx][1], d1[ty + 1][tx + 1][1]));
    float i1c2 = fmaxf(fmaxf(d1[ty][tx][2], d1[ty][tx + 1][2]), fmaxf(d1[ty + 1][tx][2], d1[ty + 1][tx + 1][2]));
    const float cu0 = prelu(bu[0], au[0]), cu1 = prelu(bu[1], au[1]), cu2 = prelu(bu[2], au[2]);
    float i3c0 = cu0, i3c1 = cu1, i3c2 = cu2;
    const int he = h + (h & 1), we = w + (w & 1);
    if (he < HW && we < HW) {
        const float* p = in3 + (((b * 256 + (he >> 1)) * 256 + (we >> 1)) * 3);
        const float x0 = p[0], x1 = p[1], x2 = p[2];
        i3c0 = fmaxf(i3c0, prelu(x0 * Wu[0] + x1 * Wu[3] + x2 * Wu[6] + bu[0], au[0]));
        i3c1 = fmaxf(i3c1, prelu(x0 * Wu[1] + x1 * Wu[4] + x2 * Wu[7] + bu[1], au[1]));
        i3c2 = fmaxf(i3c2, prelu(x0 * Wu[2] + x1 * Wu[5] + x2 * Wu[8] + bu[2], au[2]));
    }
    const int pix = ((b * HW + h) * HW + w) * 3;
    float s0 = i1c0 + in2[pix + 0] + i3c0;
    float s1 = i1c1 + in2[pix + 1] + i3c1;
    float s2 = i1c2 + in2[pix + 2] + i3c2;
    s_out[pix + 0] = s0; s_out[pix + 1] = s1; s_out[pix + 2] = s2;
    #pragma unroll
    for (int off = 32; off > 0; off >>= 1) {
        s0 += __shfl_down(s0, off); s1 += __shfl_down(s1, off); s2 += __shfl_down(s2, off);
    }
    __shared__ float red[4][3];
    const int lane = tid & 63, wave = tid >> 6;
    if (lane == 0) { red[wave][0] = s0; red[wave][1] = s1; red[wave][2] = s2; }
    __syncthreads();
    if (tid == 0) {
        const int pid = (b * 32 + blockIdx.y) * 32 + blockIdx.x;
        partials[pid * 3 + 0] = red[0][0] + red[1][0] + red[2][0] + red[3][0];
        partials[pid * 3 + 1] = red[0][1] + red[1][1] + red[2][1] + red[3][1];
        partials[pid * 3 + 2] = red[0][2] + red[1][2] + red[2][2] + red[3][2];
    }
}

__global__ __launch_bounds__(256) void k2_gate(
    const float* __restrict__ partials,
    const float* __restrict__ Wc, const float* __restrict__ bc, const float* __restrict__ ag,
    float* __restrict__ y)
{
    const int b = blockIdx.x;
    const int tid = threadIdx.x;
    float s0 = 0.f, s1 = 0.f, s2 = 0.f;
    for (int i = tid; i < 1024; i += 256) {
        const float* p = partials + (b * 1024 + i) * 3;
        s0 += p[0]; s1 += p[1]; s2 += p[2];
    }
    #pragma unroll
    for (int off = 32; off > 0; off >>= 1) {
        s0 += __shfl_down(s0, off); s1 += __shfl_down(s1, off); s2 += __shfl_down(s2, off);
    }
    __shared__ float red[4][3];
    const int lane = tid & 63, wave = tid >> 6;
    if (lane == 0) { red[wave][0] = s0; red[wave][1] = s1; red[wave][2] = s2; }
    __syncthreads();
    if (tid == 0) {
        const float inv_n = 1.f / (float)(HW * HW);
        const float g0 = (red[0][0] + red[1][0] + red[2][0] + red[3][0]) * inv_n;
        const float g1 = (red[0][1] + red[1][1] + red[2][1] + red[3][1]) * inv_n;
        const float g2 = (red[0][2] + red[1][2] + red[2][2] + red[3][2]) * inv_n;
        const float x0 = prelu(g0 * Wc[0] + g1 * Wc[3] + g2 * Wc[6] + bc[0], ag[0]);
        const float x1 = prelu(g0 * Wc[1] + g1 * Wc[4] + g2 * Wc[7] + bc[1], ag[1]);
        const float x2 = prelu(g0 * Wc[2] + g1 * Wc[5] + g2 * Wc[8] + bc[2], ag[2]);
        const float q0 = x0 * Wc[0] + x1 * Wc[3] + x2 * Wc[6] + bc[0];
        const float q1 = x0 * Wc[1] + x1 * Wc[4] + x2 * Wc[7] + bc[1];
        const float q2 = x0 * Wc[2] + x1 * Wc[5] + x2 * Wc[8] + bc[2];
        const float m = fmaxf(q0, fmaxf(q1, q2));
        const float e0 = expf(q0 - m), e1 = expf(q1 - m), e2 = expf(q2 - m);
        const float inv = 1.f / (e0 + e1 + e2);
        y[b * 3 + 0] = e0 * inv; y[b * 3 + 1] = e1 * inv; y[b * 3 + 2] = e2 * inv;
    }
}

__global__ __launch_bounds__(256) void k3_scale(float* __restrict__ out, const float* __restrict__ y)
{
    const int i = blockIdx.x * 256 + threadIdx.x;
    const int f = i * 4;
    const int b = f / (HW * HW * 3);
    const int c0 = f % 3;
    const float* yb = y + b * 3;
    const float m0 = yb[c0];
    const float m1 = yb[c0 == 2 ? 0 : c0 + 1];
    const float m2 = yb[c0 == 0 ? 2 : c0 - 1];
    float4 v = reinterpret_cast<float4*>(out)[i];
    v.x *= m0; v.y *= m1; v.z *= m2; v.w *= m0;
    reinterpret_cast<float4*>(out)[i] = v;
}

extern "C" void kernel_launch(void* const* d_in, const int* in_sizes, int n_in,
                              void* d_out, int out_size, void* d_ws, size_t ws_size,
                              hipStream_t stream)
{
    const float* in1 = (const float*)d_in[0];
    const float* in2 = (const float*)d_in[1];
    const float* in3 = (const float*)d_in[2];
    const float* Wd  = (const float*)d_in[3];
    const float* bd  = (const float*)d_in[4];
    const float* ad  = (const float*)d_in[5];
    const float* Wu  = (const float*)d_in[6];
    const float* bu  = (const float*)d_in[7];
    const float* au  = (const float*)d_in[8];
    const float* Wc  = (const float*)d_in[9];
    const float* bc  = (const float*)d_in[10];
    const float* ag  = (const float*)d_in[11];
    float* out = (float*)d_out;
    float* ws  = (float*)d_ws;

    void* args[] = { (void*)&in1, (void*)&in2, (void*)&in3,
                     (void*)&Wd, (void*)&bd, (void*)&ad,
                     (void*)&Wu, (void*)&bu, (void*)&au,
                     (void*)&Wc, (void*)&bc, (void*)&ag,
                     (void*)&out, (void*)&ws };
    const unsigned smem_bytes = (24576 + 4617 + 48 + 3 + 4) * sizeof(float);
    hipError_t err = hipLaunchCooperativeKernel((const void*)fused, dim3(256), dim3(1024),
                                                args, smem_bytes, stream);
    if (err != hipSuccess) {
        // fallback: proven 3-kernel path
        float* partials = ws;
        float* y        = partials + 8192 * 3;
        k1_compute_s<<<dim3(32, 32, 8), 256, 0, stream>>>(in1, in2, in3, Wd, bd, ad, Wu, bu, au, out, partials);
        k2_gate<<<8, 256, 0, stream>>>(partials, Wc, bc, ag, y);
        k3_scale<<<6144, 256, 0, stream>>>(out, y);
    }
}